// Round 9
// baseline (903.406 us; speedup 1.0000x reference)
//
#include <hip/hip_runtime.h>
#include <hip/hip_bf16.h>
#include <math.h>

// Problem constants (fixed by the reference file)
#define NPTS 262144
#define NP   128
#define DD   64
#define NWORDS (NPTS / 64)   // 4096 u64 ballot words per plane

// AS(4) scalar pointers for small uniform reads (planes/BN). R7 lesson: use
// POD ext_vector for AS(4) vectors (HIP float4 ctors break the host pass).
#define AS4 __attribute__((address_space(4)))
typedef float evf4 __attribute__((ext_vector_type(4)));
typedef AS4 const float* csf;
typedef AS4 const evf4*  csf4;
#define TO_CSF(p)  ((csf)(unsigned long long)(const void*)(p))
#define TO_CSF4(p) ((csf4)(unsigned long long)(const void*)(p))

// ---------------------------------------------------------------------------
// Prep: pack plane params [P][12] (normal.xyz+offs | min.xyz | max.xyz),
// transpose w2 -> w2T[j][k], zero out_feats for the atomic-max pool.
// ---------------------------------------------------------------------------
__global__ __launch_bounds__(256) void prep_kernel(
    const float* __restrict__ plane_center, const float* __restrict__ plane_normal,
    const float* __restrict__ pmin, const float* __restrict__ pmax,
    const float* __restrict__ w2,
    float* __restrict__ packed, float* __restrict__ w2T,
    float* __restrict__ out_feats)
{
    const int t = threadIdx.x;
    out_feats[blockIdx.x * 256 + t] = 0.0f;          // grid = 64 blocks
    if (blockIdx.x == 0 && t < NP) {
        float n0 = plane_normal[t*3+0], n1 = plane_normal[t*3+1], n2 = plane_normal[t*3+2];
        float c0 = plane_center[t*3+0], c1 = plane_center[t*3+1], c2 = plane_center[t*3+2];
        float off = (c0*n0 + c1*n1) + c2*n2;          // matches jnp.sum order
        float4* pp = reinterpret_cast<float4*>(packed) + t * 3;
        pp[0] = make_float4(n0, n1, n2, off);
        pp[1] = make_float4(pmin[t*3+0], pmin[t*3+1], pmin[t*3+2], 0.0f);
        pp[2] = make_float4(pmax[t*3+0], pmax[t*3+1], pmax[t*3+2], 0.0f);
    }
    if (blockIdx.x == 1) {
#pragma unroll
        for (int u = 0; u < 16; ++u) {
            const int e = u * 256 + t;               // e = j*64 + k
            const int j = e >> 6, k = e & 63;
            w2T[e] = w2[k * DD + j];
        }
    }
}

// ---------------------------------------------------------------------------
// Fused per-point kernel, round-17 (resubmit; R8 bench was an infra
// failure, kernel never ran): R16 (phase-overlapped mask) with the spk
// STAGING BUG FIXED. R16 failed (absmax 0.13) because the third staging
// line overwrote dp[128..255] with sp[256..383] -> planes ~42-85 got wrong
// params. Clean staging now: dp[t]=sp[t] (0..255), t<128: dp[256+t]=
// sp[256+t] (256..383). Theory (untested by R16's failure): fc (~160us,
// VALU+LDS) and Phase C (~130us, 537MB scattered stores) serialize in
// lockstep; moving score-independent C work (geometry + out_mask, 134MB)
// into Phase A's shadow overlaps HBM writes with VALU/LDS. spk = 6KB LDS
// (54KB total -> hw cap 2 blocks/CU vs 3; measured avg residency was ~2
// anyway -- watch OccupancyPercent). Same FP ops/values/order as R9 ->
// bit-identical, absmax 2.98e-8. XCD swizzle kept (R15: -20us).
// ---------------------------------------------------------------------------
#define C1PLANE(P, MKB) {                                                     \
    const evf4 nrm = spk[(P)*3+0];                                            \
    const evf4 mn  = spk[(P)*3+1];                                            \
    const evf4 mx  = spk[(P)*3+2];                                            \
    float d = fabsf(fmaf(c2, nrm.z, fmaf(c1, nrm.y, c0 * nrm.x)) - nrm.w);    \
    bool ok0 = (mx.x == 0.0f) | ((c0 >= mn.x) & (c0 < mx.x));                 \
    bool ok1 = (mx.y == 0.0f) | ((c1 >= mn.y) & (c1 < mx.y));                 \
    bool ok2 = (mx.z == 0.0f) | ((c2 >= mn.z) & (c2 < mx.z));                 \
    bool mk  = ok0 & ok1 & ok2 & (d < 0.1f);                                  \
    out_mask[((size_t)(P) << 18) + n] = mk ? 1.0f : 0.0f;                     \
    MKB |= ((unsigned long long)mk) << ((P) & 63); }

__global__ __launch_bounds__(256) void fused_kernel(
    const float* __restrict__ feature, const float* __restrict__ feature_geo,
    const float* __restrict__ xyz, const float* __restrict__ centers,
    const float* __restrict__ packed,
    const float* __restrict__ w1, const float* __restrict__ b1,
    const float* __restrict__ g1, const float* __restrict__ be1,
    const float* __restrict__ m1, const float* __restrict__ v1,
    const float* __restrict__ w2T, const float* __restrict__ b2,
    const float* __restrict__ g2, const float* __restrict__ be2,
    const float* __restrict__ m2, const float* __restrict__ v2,
    const float* __restrict__ w3, const float* __restrict__ b3,
    float* __restrict__ h2_out,
    float* __restrict__ out_sm, float* __restrict__ out_mask,
    float* __restrict__ out_on, float* __restrict__ out_off,
    unsigned long long* __restrict__ hitOn, unsigned long long* __restrict__ hitOff)
{
    __shared__ float sw1[128 * DD];    // 32 KB, row-major [k][j] like w1
    __shared__ float sw2[DD * DD];     // 16 KB, w2T layout [j][k]
    __shared__ evf4  spk[NP * 3];      // 6 KB plane params (nrm|mn|mx)
    const int t = threadIdx.x;
    // XCD-aware bijective swizzle: XCD = bid%8; contiguous 128-block span
    // per XCD for L2 write locality (R15: -20us).
    const int bs = (blockIdx.x & 7) * 128 + (blockIdx.x >> 3);
    const int n = bs * 256 + t;
    const int lane = t & 63;
    const int word = n >> 6;

    // stage weights (coalesced float4; 12 per thread) + plane params (384 f4)
    {
        const float4* s1 = reinterpret_cast<const float4*>(w1);
        const float4* s2 = reinterpret_cast<const float4*>(w2T);
        float4* d1 = reinterpret_cast<float4*>(sw1);
        float4* d2 = reinterpret_cast<float4*>(sw2);
#pragma unroll
        for (int k = 0; k < 8; ++k) d1[t + k * 256] = s1[t + k * 256];
#pragma unroll
        for (int k = 0; k < 4; ++k) d2[t + k * 256] = s2[t + k * 256];
        const float4* sp = reinterpret_cast<const float4*>(packed);
        float4* dp = reinterpret_cast<float4*>(spk);
        dp[t] = sp[t];                               // 0..255
        if (t < 128) dp[256 + t] = sp[256 + t];      // 256..383
    }

    // cloud coords (issue early; used by C1 inside Phase A)
    const csf cc = TO_CSF(centers);
    const float c0 = xyz[n*3+0] + cc[0];
    const float c1 = xyz[n*3+1] + cc[1];
    const float c2 = xyz[n*3+2] + cc[2];

    __syncthreads();

    float acc[DD];
#pragma unroll
    for (int j = 0; j < DD; ++j) acc[j] = 0.0f;

    unsigned long long mkb0 = 0ULL, mkb1 = 0ULL;

    // ---- Phase A: fc1 from LDS (q rolled) + C1 mask work (4 planes/iter) ----
    const float4* fA = reinterpret_cast<const float4*>(feature) + (size_t)n * 16;
    const float4* fB = reinterpret_cast<const float4*>(feature_geo) + (size_t)n * 16;
#pragma unroll 1
    for (int q = 0; q < 16; ++q) {
        const float4 fv = fA[q];
        const evf4* wr = reinterpret_cast<const evf4*>(sw1 + q * 4 * DD);
#pragma unroll
        for (int j4 = 0; j4 < 16; ++j4) { const evf4 w = wr[j4];
            acc[4*j4+0] = fmaf(fv.x, w.x, acc[4*j4+0]);
            acc[4*j4+1] = fmaf(fv.x, w.y, acc[4*j4+1]);
            acc[4*j4+2] = fmaf(fv.x, w.z, acc[4*j4+2]);
            acc[4*j4+3] = fmaf(fv.x, w.w, acc[4*j4+3]); }
#pragma unroll
        for (int j4 = 0; j4 < 16; ++j4) { const evf4 w = wr[16 + j4];
            acc[4*j4+0] = fmaf(fv.y, w.x, acc[4*j4+0]);
            acc[4*j4+1] = fmaf(fv.y, w.y, acc[4*j4+1]);
            acc[4*j4+2] = fmaf(fv.y, w.z, acc[4*j4+2]);
            acc[4*j4+3] = fmaf(fv.y, w.w, acc[4*j4+3]); }
#pragma unroll
        for (int j4 = 0; j4 < 16; ++j4) { const evf4 w = wr[32 + j4];
            acc[4*j4+0] = fmaf(fv.z, w.x, acc[4*j4+0]);
            acc[4*j4+1] = fmaf(fv.z, w.y, acc[4*j4+1]);
            acc[4*j4+2] = fmaf(fv.z, w.z, acc[4*j4+2]);
            acc[4*j4+3] = fmaf(fv.z, w.w, acc[4*j4+3]); }
#pragma unroll
        for (int j4 = 0; j4 < 16; ++j4) { const evf4 w = wr[48 + j4];
            acc[4*j4+0] = fmaf(fv.w, w.x, acc[4*j4+0]);
            acc[4*j4+1] = fmaf(fv.w, w.y, acc[4*j4+1]);
            acc[4*j4+2] = fmaf(fv.w, w.z, acc[4*j4+2]);
            acc[4*j4+3] = fmaf(fv.w, w.w, acc[4*j4+3]); }
        // C1: planes 4q..4q+3 (geometry + mask store + bit save)
        C1PLANE(4*q + 0, mkb0)
        C1PLANE(4*q + 1, mkb0)
        C1PLANE(4*q + 2, mkb0)
        C1PLANE(4*q + 3, mkb0)
    }
#pragma unroll 1
    for (int q = 0; q < 16; ++q) {
        const float4 fv = fB[q];
        const evf4* wr = reinterpret_cast<const evf4*>(sw1 + (DD + q * 4) * DD);
#pragma unroll
        for (int j4 = 0; j4 < 16; ++j4) { const evf4 w = wr[j4];
            acc[4*j4+0] = fmaf(fv.x, w.x, acc[4*j4+0]);
            acc[4*j4+1] = fmaf(fv.x, w.y, acc[4*j4+1]);
            acc[4*j4+2] = fmaf(fv.x, w.z, acc[4*j4+2]);
            acc[4*j4+3] = fmaf(fv.x, w.w, acc[4*j4+3]); }
#pragma unroll
        for (int j4 = 0; j4 < 16; ++j4) { const evf4 w = wr[16 + j4];
            acc[4*j4+0] = fmaf(fv.y, w.x, acc[4*j4+0]);
            acc[4*j4+1] = fmaf(fv.y, w.y, acc[4*j4+1]);
            acc[4*j4+2] = fmaf(fv.y, w.z, acc[4*j4+2]);
            acc[4*j4+3] = fmaf(fv.y, w.w, acc[4*j4+3]); }
#pragma unroll
        for (int j4 = 0; j4 < 16; ++j4) { const evf4 w = wr[32 + j4];
            acc[4*j4+0] = fmaf(fv.z, w.x, acc[4*j4+0]);
            acc[4*j4+1] = fmaf(fv.z, w.y, acc[4*j4+1]);
            acc[4*j4+2] = fmaf(fv.z, w.z, acc[4*j4+2]);
            acc[4*j4+3] = fmaf(fv.z, w.w, acc[4*j4+3]); }
#pragma unroll
        for (int j4 = 0; j4 < 16; ++j4) { const evf4 w = wr[48 + j4];
            acc[4*j4+0] = fmaf(fv.w, w.x, acc[4*j4+0]);
            acc[4*j4+1] = fmaf(fv.w, w.y, acc[4*j4+1]);
            acc[4*j4+2] = fmaf(fv.w, w.z, acc[4*j4+2]);
            acc[4*j4+3] = fmaf(fv.w, w.w, acc[4*j4+3]); }
        // C1: planes 64+4q..64+4q+3
        C1PLANE(64 + 4*q + 0, mkb1)
        C1PLANE(64 + 4*q + 1, mkb1)
        C1PLANE(64 + 4*q + 2, mkb1)
        C1PLANE(64 + 4*q + 3, mkb1)
    }
    // BN1 + ReLU in place (exact same arithmetic/order as R3-R9)
    {
        const csf g1c = TO_CSF(g1), v1c = TO_CSF(v1), b1c = TO_CSF(b1),
                  m1c = TO_CSF(m1), be1c = TO_CSF(be1);
#pragma unroll
        for (int j = 0; j < DD; ++j) {
            float sc = g1c[j] * (1.0f / sqrtf(v1c[j] + 1e-5f));
            float h  = fmaf(acc[j] + b1c[j] - m1c[j], sc, be1c[j]);
            acc[j] = fmaxf(h, 0.0f);
        }
    }

    // ---- Phase B: fc2 from LDS w2T rows + BN2 + ReLU + fc3 + h2 store ----
    const csf g2c = TO_CSF(g2), v2c = TO_CSF(v2), b2c = TO_CSF(b2),
              m2c = TO_CSF(m2), be2c = TO_CSF(be2), w3c = TO_CSF(w3);
    float s = 0.0f;
    float4* o = reinterpret_cast<float4*>(h2_out) + (size_t)n * 16;
#pragma unroll 1
    for (int jq = 0; jq < 16; ++jq) {
        const evf4* r0 = reinterpret_cast<const evf4*>(sw2 + (4*jq + 0) * DD);
        const evf4* r1 = reinterpret_cast<const evf4*>(sw2 + (4*jq + 1) * DD);
        const evf4* r2 = reinterpret_cast<const evf4*>(sw2 + (4*jq + 2) * DD);
        const evf4* r3 = reinterpret_cast<const evf4*>(sw2 + (4*jq + 3) * DD);
        float a0 = 0.0f, a1 = 0.0f, a2 = 0.0f, a3 = 0.0f;
#pragma unroll
        for (int k4 = 0; k4 < 16; ++k4) {
            const evf4 w0 = r0[k4], w1v = r1[k4], w2v = r2[k4], w3v = r3[k4];
            const float h0 = acc[4*k4+0], h1v = acc[4*k4+1],
                        h2v = acc[4*k4+2], h3v = acc[4*k4+3];
            a0 = fmaf(h0, w0.x, a0); a0 = fmaf(h1v, w0.y, a0);
            a0 = fmaf(h2v, w0.z, a0); a0 = fmaf(h3v, w0.w, a0);
            a1 = fmaf(h0, w1v.x, a1); a1 = fmaf(h1v, w1v.y, a1);
            a1 = fmaf(h2v, w1v.z, a1); a1 = fmaf(h3v, w1v.w, a1);
            a2 = fmaf(h0, w2v.x, a2); a2 = fmaf(h1v, w2v.y, a2);
            a2 = fmaf(h2v, w2v.z, a2); a2 = fmaf(h3v, w2v.w, a2);
            a3 = fmaf(h0, w3v.x, a3); a3 = fmaf(h1v, w3v.y, a3);
            a3 = fmaf(h2v, w3v.z, a3); a3 = fmaf(h3v, w3v.w, a3);
        }
        float hv[4] = {a0, a1, a2, a3};
#pragma unroll
        for (int u = 0; u < 4; ++u) {
            const int jj = 4*jq + u;
            float sc = g2c[jj] * (1.0f / sqrtf(v2c[jj] + 1e-5f));
            float h  = fmaf(hv[u] + b2c[jj] - m2c[jj], sc, be2c[jj]);
            h = fmaxf(h, 0.0f);
            hv[u] = h;
            s = fmaf(h, w3c[jj], s);
        }
        o[jq] = make_float4(hv[0], hv[1], hv[2], hv[3]);
    }
    s += TO_CSF(b3)[0];
    const float score = fmaxf(s, 0.0f);

    // sigmoid(score) > 0.5 via XLA-style logistic expansion (score >= 0)
    const bool on = (0.5f + 0.5f * tanhf(0.5f * score)) > 0.5f;

    // ---- Phase C2: pure drain — sm/on/off stores + ballots from saved bits ----
#pragma unroll 1
    for (int p = 0; p < NP; ++p) {
        const unsigned long long wbits = (p & 64) ? mkb1 : mkb0;
        const bool mk = (wbits >> (p & 63)) & 1ULL;
        const size_t idx = ((size_t)p << 18) + n;
        const bool mon  = mk & on;
        const bool moff = mk & (!on);
        out_sm[idx]   = mk ? score : 0.0f;
        out_on[idx]   = mon ? 1.0f : 0.0f;
        out_off[idx]  = moff ? 1.0f : 0.0f;
        unsigned long long bOn  = __ballot(mon);
        unsigned long long bOff = __ballot(moff);
        if (lane == 0) {
            hitOn [(size_t)p * NWORDS + word] = bOn;
            hitOff[(size_t)p * NWORDS + word] = bOff;
        }
    }
}

// ---------------------------------------------------------------------------
// Pool, round-14 form (kept): PLANE-OWNER GATHER. Block = (plane, side,
// chunk/16); scan 256 ballot words (coalesced 512B/wave + ballot/shfl walk),
// one coalesced 256B gather h2[n*64+lane] per hit (ILP-2), 4-wave LDS
// reduce, 1 atomicMax per dim (262K atomics, <=16 contenders/address).
// fmax order-independent -> bit-identical. ~30us.
// ---------------------------------------------------------------------------
__global__ __launch_bounds__(256) void pool_kernel(
    const float* __restrict__ h2,
    const unsigned long long* __restrict__ hitOn,
    const unsigned long long* __restrict__ hitOff,
    int* __restrict__ out_feats_i)
{
    __shared__ float sacc[4][DD];
    const int t = threadIdx.x;
    const int lane = t & 63;
    const int wv = t >> 6;

    const int bid   = blockIdx.x;          // 4096 = 128 planes * 2 sides * 16 chunks
    const int p     = bid >> 5;
    const int side  = (bid >> 4) & 1;
    const int chunk = bid & 15;
    const unsigned long long* hsrc = side ? hitOff : hitOn;

    // this wave's 64 words of the plane's ballot bitmap (coalesced 512B)
    const int wbase = chunk * 256 + wv * 64;
    const unsigned long long myw = hsrc[(size_t)p * NWORDS + wbase + lane];

    float acc = 0.0f;
    unsigned long long act = __ballot(myw != 0ULL);
    while (act) {
        const int l = __builtin_ctzll(act);
        act &= act - 1;
        unsigned long long w = __shfl(myw, l, 64);   // wave-uniform word
        const size_t nbase = (size_t)(wbase + l) * 64;
        while (w) {
            const int b0 = __builtin_ctzll(w); w &= w - 1;
            if (w) {
                const int b1 = __builtin_ctzll(w); w &= w - 1;
                const float v0 = h2[(nbase + b0) * DD + lane];
                const float v1 = h2[(nbase + b1) * DD + lane];
                acc = fmaxf(acc, v0);
                acc = fmaxf(acc, v1);
            } else {
                const float v0 = h2[(nbase + b0) * DD + lane];
                acc = fmaxf(acc, v0);
            }
        }
    }

    sacc[wv][lane] = acc;
    __syncthreads();
    if (t < DD) {
        const float m = fmaxf(fmaxf(sacc[0][t], sacc[1][t]),
                              fmaxf(sacc[2][t], sacc[3][t]));
        if (m != 0.0f)
            atomicMax(&out_feats_i[side * NP * DD + p * DD + t], __float_as_int(m));
    }
}

extern "C" void kernel_launch(void* const* d_in, const int* in_sizes, int n_in,
                              void* d_out, int out_size, void* d_ws, size_t ws_size,
                              hipStream_t stream) {
    const float* feature      = (const float*)d_in[0];
    const float* feature_geo  = (const float*)d_in[1];
    const float* xyz          = (const float*)d_in[2];
    const float* centers      = (const float*)d_in[3];
    const float* plane_center = (const float*)d_in[4];
    const float* plane_normal = (const float*)d_in[5];
    const float* pmin         = (const float*)d_in[6];
    const float* pmax         = (const float*)d_in[7];
    const float* w1 = (const float*)d_in[8];
    const float* b1 = (const float*)d_in[9];
    const float* g1 = (const float*)d_in[10];
    const float* be1 = (const float*)d_in[11];
    const float* m1 = (const float*)d_in[12];
    const float* v1 = (const float*)d_in[13];
    const float* w2 = (const float*)d_in[14];
    const float* b2 = (const float*)d_in[15];
    const float* g2 = (const float*)d_in[16];
    const float* be2 = (const float*)d_in[17];
    const float* m2 = (const float*)d_in[18];
    const float* v2 = (const float*)d_in[19];
    const float* w3 = (const float*)d_in[20];
    const float* b3 = (const float*)d_in[21];

    float* out = (float*)d_out;
    const size_t PN = (size_t)NP * NPTS;
    float* out_sm    = out;
    float* out_mask  = out + PN;
    float* out_on    = out + 2 * PN;
    float* out_off   = out + 3 * PN;
    float* out_feats = out + 4 * PN;

    // workspace carve (~73 MB)
    float* h2     = (float*)d_ws;                                // N*64 f32 (64 MB)
    unsigned long long* hitOn  = (unsigned long long*)(h2 + (size_t)NPTS * DD);
    unsigned long long* hitOff = hitOn + (size_t)NP * NWORDS;
    float* packed = (float*)(hitOff + (size_t)NP * NWORDS);      // P*12 f32
    float* w2T    = packed + NP * 12;                            // 64*64 f32

    prep_kernel<<<64, 256, 0, stream>>>(
        plane_center, plane_normal, pmin, pmax, w2, packed, w2T, out_feats);
    fused_kernel<<<NPTS / 256, 256, 0, stream>>>(
        feature, feature_geo, xyz, centers, packed,
        w1, b1, g1, be1, m1, v1, w2T, b2, g2, be2, m2, v2, w3, b3,
        h2, out_sm, out_mask, out_on, out_off, hitOn, hitOff);
    pool_kernel<<<4096, 256, 0, stream>>>(h2, hitOn, hitOff, (int*)out_feats);
}

// Round 10
// 796.034 us; speedup vs baseline: 1.1349x; 1.1349x over previous
//
#include <hip/hip_runtime.h>
#include <hip/hip_bf16.h>
#include <math.h>

// Problem constants (fixed by the reference file)
#define NPTS 262144
#define NP   128
#define DD   64
#define NWORDS (NPTS / 64)   // 4096 u64 ballot words per plane

// AS(4) scalar pointers for small uniform reads (planes/BN). R7 lesson: use
// POD ext_vector for AS(4) vectors (HIP float4 ctors break the host pass).
#define AS4 __attribute__((address_space(4)))
typedef float evf4 __attribute__((ext_vector_type(4)));
typedef AS4 const float* csf;
typedef AS4 const evf4*  csf4;
#define TO_CSF(p)  ((csf)(unsigned long long)(const void*)(p))
#define TO_CSF4(p) ((csf4)(unsigned long long)(const void*)(p))

// ---------------------------------------------------------------------------
// Prep: pack plane params SoA for the fused kernel's 5KB LDS copy:
//   packed[0..511]   : float4 nrm4[128]  (normal.xyz | offs)
//   packed[512..1279]: bounds[768] = mnx[128]|mny|mnz|mxx|mxy|mxz
// Also transpose w2 -> w2T[j][k], zero out_feats for the atomic-max pool.
// ---------------------------------------------------------------------------
__global__ __launch_bounds__(256) void prep_kernel(
    const float* __restrict__ plane_center, const float* __restrict__ plane_normal,
    const float* __restrict__ pmin, const float* __restrict__ pmax,
    const float* __restrict__ w2,
    float* __restrict__ packed, float* __restrict__ w2T,
    float* __restrict__ out_feats)
{
    const int t = threadIdx.x;
    out_feats[blockIdx.x * 256 + t] = 0.0f;          // grid = 64 blocks
    if (blockIdx.x == 0 && t < NP) {
        float n0 = plane_normal[t*3+0], n1 = plane_normal[t*3+1], n2 = plane_normal[t*3+2];
        float c0 = plane_center[t*3+0], c1 = plane_center[t*3+1], c2 = plane_center[t*3+2];
        float off = (c0*n0 + c1*n1) + c2*n2;          // matches jnp.sum order
        reinterpret_cast<float4*>(packed)[t] = make_float4(n0, n1, n2, off);
        float* bnd = packed + 512;
        bnd[t]         = pmin[t*3+0];
        bnd[128 + t]   = pmin[t*3+1];
        bnd[256 + t]   = pmin[t*3+2];
        bnd[384 + t]   = pmax[t*3+0];
        bnd[512 + t]   = pmax[t*3+1];
        bnd[640 + t]   = pmax[t*3+2];
    }
    if (blockIdx.x == 1) {
#pragma unroll
        for (int u = 0; u < 16; ++u) {
            const int e = u * 256 + t;               // e = j*64 + k
            const int j = e >> 6, k = e & 63;
            w2T[e] = w2[k * DD + j];
        }
    }
}

// ---------------------------------------------------------------------------
// Fused per-point kernel, round-18: PHASE-OVERLAPPED MASK at 3 BLOCKS/CU.
// R17 post-mortem: overlap structure ran but the 6KB AoS spk pushed LDS to
// 54KB -> hw residency 3->2 blocks/CU, OccupancyPercent 24->11.7, fused
// 310->427 (latency-bound kernel, half the TLP). Fix: SoA plane params --
// evf4 snrm[128] (2KB) + float sbnd[768] (3KB) -> LDS = 32+16+2+3 = 53KB
// (54272B; 3x = 162816 <= 163840) -> 3 blocks/CU restored. C1PLANE reads
// 1 b128 + 6 b32 wave-uniform broadcasts. Same compares/FP ops/order as
// R17/R9 -> bit-identical, absmax 2.98e-8. Theory under test (now at full
// occupancy): score-independent mask work (geometry + out_mask, 134MB)
// hides under Phase A's fc window instead of serializing after it.
// XCD swizzle kept (R15: -20us). VGPR must stay <=170 for 3 waves/SIMD
// (R17: 136).
// ---------------------------------------------------------------------------
#define C1PLANE(P, MKB) {                                                     \
    const evf4 nrm = snrm[(P)];                                               \
    const float mnx = sbnd[(P)], mny = sbnd[128+(P)], mnz = sbnd[256+(P)];    \
    const float mxx = sbnd[384+(P)], mxy = sbnd[512+(P)], mxz = sbnd[640+(P)];\
    float d = fabsf(fmaf(c2, nrm.z, fmaf(c1, nrm.y, c0 * nrm.x)) - nrm.w);    \
    bool ok0 = (mxx == 0.0f) | ((c0 >= mnx) & (c0 < mxx));                    \
    bool ok1 = (mxy == 0.0f) | ((c1 >= mny) & (c1 < mxy));                    \
    bool ok2 = (mxz == 0.0f) | ((c2 >= mnz) & (c2 < mxz));                    \
    bool mk  = ok0 & ok1 & ok2 & (d < 0.1f);                                  \
    out_mask[((size_t)(P) << 18) + n] = mk ? 1.0f : 0.0f;                     \
    MKB |= ((unsigned long long)mk) << ((P) & 63); }

__global__ __launch_bounds__(256) void fused_kernel(
    const float* __restrict__ feature, const float* __restrict__ feature_geo,
    const float* __restrict__ xyz, const float* __restrict__ centers,
    const float* __restrict__ packed,
    const float* __restrict__ w1, const float* __restrict__ b1,
    const float* __restrict__ g1, const float* __restrict__ be1,
    const float* __restrict__ m1, const float* __restrict__ v1,
    const float* __restrict__ w2T, const float* __restrict__ b2,
    const float* __restrict__ g2, const float* __restrict__ be2,
    const float* __restrict__ m2, const float* __restrict__ v2,
    const float* __restrict__ w3, const float* __restrict__ b3,
    float* __restrict__ h2_out,
    float* __restrict__ out_sm, float* __restrict__ out_mask,
    float* __restrict__ out_on, float* __restrict__ out_off,
    unsigned long long* __restrict__ hitOn, unsigned long long* __restrict__ hitOff)
{
    __shared__ float sw1[128 * DD];    // 32 KB, row-major [k][j] like w1
    __shared__ float sw2[DD * DD];     // 16 KB, w2T layout [j][k]
    __shared__ evf4  snrm[NP];         // 2 KB  (normal.xyz | offs)
    __shared__ float sbnd[768];        // 3 KB  mnx|mny|mnz|mxx|mxy|mxz
    const int t = threadIdx.x;
    // XCD-aware bijective swizzle: XCD = bid%8; contiguous 128-block span
    // per XCD for L2 write locality (R15: -20us).
    const int bs = (blockIdx.x & 7) * 128 + (blockIdx.x >> 3);
    const int n = bs * 256 + t;
    const int lane = t & 63;
    const int word = n >> 6;

    // stage weights (coalesced float4; 12 per thread) + SoA plane params
    {
        const float4* s1 = reinterpret_cast<const float4*>(w1);
        const float4* s2 = reinterpret_cast<const float4*>(w2T);
        float4* d1 = reinterpret_cast<float4*>(sw1);
        float4* d2 = reinterpret_cast<float4*>(sw2);
#pragma unroll
        for (int k = 0; k < 8; ++k) d1[t + k * 256] = s1[t + k * 256];
#pragma unroll
        for (int k = 0; k < 4; ++k) d2[t + k * 256] = s2[t + k * 256];
        const float4* sp = reinterpret_cast<const float4*>(packed);
        if (t < 128) reinterpret_cast<float4*>(snrm)[t] = sp[t];
        const float* gb = packed + 512;
        sbnd[t]       = gb[t];
        sbnd[256 + t] = gb[256 + t];
        sbnd[512 + t] = gb[512 + t];
    }

    // cloud coords (issue early; used by C1 inside Phase A)
    const csf cc = TO_CSF(centers);
    const float c0 = xyz[n*3+0] + cc[0];
    const float c1 = xyz[n*3+1] + cc[1];
    const float c2 = xyz[n*3+2] + cc[2];

    __syncthreads();

    float acc[DD];
#pragma unroll
    for (int j = 0; j < DD; ++j) acc[j] = 0.0f;

    unsigned long long mkb0 = 0ULL, mkb1 = 0ULL;

    // ---- Phase A: fc1 from LDS (q rolled) + C1 mask work (4 planes/iter) ----
    const float4* fA = reinterpret_cast<const float4*>(feature) + (size_t)n * 16;
    const float4* fB = reinterpret_cast<const float4*>(feature_geo) + (size_t)n * 16;
#pragma unroll 1
    for (int q = 0; q < 16; ++q) {
        const float4 fv = fA[q];
        const evf4* wr = reinterpret_cast<const evf4*>(sw1 + q * 4 * DD);
#pragma unroll
        for (int j4 = 0; j4 < 16; ++j4) { const evf4 w = wr[j4];
            acc[4*j4+0] = fmaf(fv.x, w.x, acc[4*j4+0]);
            acc[4*j4+1] = fmaf(fv.x, w.y, acc[4*j4+1]);
            acc[4*j4+2] = fmaf(fv.x, w.z, acc[4*j4+2]);
            acc[4*j4+3] = fmaf(fv.x, w.w, acc[4*j4+3]); }
#pragma unroll
        for (int j4 = 0; j4 < 16; ++j4) { const evf4 w = wr[16 + j4];
            acc[4*j4+0] = fmaf(fv.y, w.x, acc[4*j4+0]);
            acc[4*j4+1] = fmaf(fv.y, w.y, acc[4*j4+1]);
            acc[4*j4+2] = fmaf(fv.y, w.z, acc[4*j4+2]);
            acc[4*j4+3] = fmaf(fv.y, w.w, acc[4*j4+3]); }
#pragma unroll
        for (int j4 = 0; j4 < 16; ++j4) { const evf4 w = wr[32 + j4];
            acc[4*j4+0] = fmaf(fv.z, w.x, acc[4*j4+0]);
            acc[4*j4+1] = fmaf(fv.z, w.y, acc[4*j4+1]);
            acc[4*j4+2] = fmaf(fv.z, w.z, acc[4*j4+2]);
            acc[4*j4+3] = fmaf(fv.z, w.w, acc[4*j4+3]); }
#pragma unroll
        for (int j4 = 0; j4 < 16; ++j4) { const evf4 w = wr[48 + j4];
            acc[4*j4+0] = fmaf(fv.w, w.x, acc[4*j4+0]);
            acc[4*j4+1] = fmaf(fv.w, w.y, acc[4*j4+1]);
            acc[4*j4+2] = fmaf(fv.w, w.z, acc[4*j4+2]);
            acc[4*j4+3] = fmaf(fv.w, w.w, acc[4*j4+3]); }
        // C1: planes 4q..4q+3 (geometry + mask store + bit save)
        C1PLANE(4*q + 0, mkb0)
        C1PLANE(4*q + 1, mkb0)
        C1PLANE(4*q + 2, mkb0)
        C1PLANE(4*q + 3, mkb0)
    }
#pragma unroll 1
    for (int q = 0; q < 16; ++q) {
        const float4 fv = fB[q];
        const evf4* wr = reinterpret_cast<const evf4*>(sw1 + (DD + q * 4) * DD);
#pragma unroll
        for (int j4 = 0; j4 < 16; ++j4) { const evf4 w = wr[j4];
            acc[4*j4+0] = fmaf(fv.x, w.x, acc[4*j4+0]);
            acc[4*j4+1] = fmaf(fv.x, w.y, acc[4*j4+1]);
            acc[4*j4+2] = fmaf(fv.x, w.z, acc[4*j4+2]);
            acc[4*j4+3] = fmaf(fv.x, w.w, acc[4*j4+3]); }
#pragma unroll
        for (int j4 = 0; j4 < 16; ++j4) { const evf4 w = wr[16 + j4];
            acc[4*j4+0] = fmaf(fv.y, w.x, acc[4*j4+0]);
            acc[4*j4+1] = fmaf(fv.y, w.y, acc[4*j4+1]);
            acc[4*j4+2] = fmaf(fv.y, w.z, acc[4*j4+2]);
            acc[4*j4+3] = fmaf(fv.y, w.w, acc[4*j4+3]); }
#pragma unroll
        for (int j4 = 0; j4 < 16; ++j4) { const evf4 w = wr[32 + j4];
            acc[4*j4+0] = fmaf(fv.z, w.x, acc[4*j4+0]);
            acc[4*j4+1] = fmaf(fv.z, w.y, acc[4*j4+1]);
            acc[4*j4+2] = fmaf(fv.z, w.z, acc[4*j4+2]);
            acc[4*j4+3] = fmaf(fv.z, w.w, acc[4*j4+3]); }
#pragma unroll
        for (int j4 = 0; j4 < 16; ++j4) { const evf4 w = wr[48 + j4];
            acc[4*j4+0] = fmaf(fv.w, w.x, acc[4*j4+0]);
            acc[4*j4+1] = fmaf(fv.w, w.y, acc[4*j4+1]);
            acc[4*j4+2] = fmaf(fv.w, w.z, acc[4*j4+2]);
            acc[4*j4+3] = fmaf(fv.w, w.w, acc[4*j4+3]); }
        // C1: planes 64+4q..64+4q+3
        C1PLANE(64 + 4*q + 0, mkb1)
        C1PLANE(64 + 4*q + 1, mkb1)
        C1PLANE(64 + 4*q + 2, mkb1)
        C1PLANE(64 + 4*q + 3, mkb1)
    }
    // BN1 + ReLU in place (exact same arithmetic/order as R3-R9)
    {
        const csf g1c = TO_CSF(g1), v1c = TO_CSF(v1), b1c = TO_CSF(b1),
                  m1c = TO_CSF(m1), be1c = TO_CSF(be1);
#pragma unroll
        for (int j = 0; j < DD; ++j) {
            float sc = g1c[j] * (1.0f / sqrtf(v1c[j] + 1e-5f));
            float h  = fmaf(acc[j] + b1c[j] - m1c[j], sc, be1c[j]);
            acc[j] = fmaxf(h, 0.0f);
        }
    }

    // ---- Phase B: fc2 from LDS w2T rows + BN2 + ReLU + fc3 + h2 store ----
    const csf g2c = TO_CSF(g2), v2c = TO_CSF(v2), b2c = TO_CSF(b2),
              m2c = TO_CSF(m2), be2c = TO_CSF(be2), w3c = TO_CSF(w3);
    float s = 0.0f;
    float4* o = reinterpret_cast<float4*>(h2_out) + (size_t)n * 16;
#pragma unroll 1
    for (int jq = 0; jq < 16; ++jq) {
        const evf4* r0 = reinterpret_cast<const evf4*>(sw2 + (4*jq + 0) * DD);
        const evf4* r1 = reinterpret_cast<const evf4*>(sw2 + (4*jq + 1) * DD);
        const evf4* r2 = reinterpret_cast<const evf4*>(sw2 + (4*jq + 2) * DD);
        const evf4* r3 = reinterpret_cast<const evf4*>(sw2 + (4*jq + 3) * DD);
        float a0 = 0.0f, a1 = 0.0f, a2 = 0.0f, a3 = 0.0f;
#pragma unroll
        for (int k4 = 0; k4 < 16; ++k4) {
            const evf4 w0 = r0[k4], w1v = r1[k4], w2v = r2[k4], w3v = r3[k4];
            const float h0 = acc[4*k4+0], h1v = acc[4*k4+1],
                        h2v = acc[4*k4+2], h3v = acc[4*k4+3];
            a0 = fmaf(h0, w0.x, a0); a0 = fmaf(h1v, w0.y, a0);
            a0 = fmaf(h2v, w0.z, a0); a0 = fmaf(h3v, w0.w, a0);
            a1 = fmaf(h0, w1v.x, a1); a1 = fmaf(h1v, w1v.y, a1);
            a1 = fmaf(h2v, w1v.z, a1); a1 = fmaf(h3v, w1v.w, a1);
            a2 = fmaf(h0, w2v.x, a2); a2 = fmaf(h1v, w2v.y, a2);
            a2 = fmaf(h2v, w2v.z, a2); a2 = fmaf(h3v, w2v.w, a2);
            a3 = fmaf(h0, w3v.x, a3); a3 = fmaf(h1v, w3v.y, a3);
            a3 = fmaf(h2v, w3v.z, a3); a3 = fmaf(h3v, w3v.w, a3);
        }
        float hv[4] = {a0, a1, a2, a3};
#pragma unroll
        for (int u = 0; u < 4; ++u) {
            const int jj = 4*jq + u;
            float sc = g2c[jj] * (1.0f / sqrtf(v2c[jj] + 1e-5f));
            float h  = fmaf(hv[u] + b2c[jj] - m2c[jj], sc, be2c[jj]);
            h = fmaxf(h, 0.0f);
            hv[u] = h;
            s = fmaf(h, w3c[jj], s);
        }
        o[jq] = make_float4(hv[0], hv[1], hv[2], hv[3]);
    }
    s += TO_CSF(b3)[0];
    const float score = fmaxf(s, 0.0f);

    // sigmoid(score) > 0.5 via XLA-style logistic expansion (score >= 0)
    const bool on = (0.5f + 0.5f * tanhf(0.5f * score)) > 0.5f;

    // ---- Phase C2: pure drain — sm/on/off stores + ballots from saved bits ----
#pragma unroll 1
    for (int p = 0; p < NP; ++p) {
        const unsigned long long wbits = (p & 64) ? mkb1 : mkb0;
        const bool mk = (wbits >> (p & 63)) & 1ULL;
        const size_t idx = ((size_t)p << 18) + n;
        const bool mon  = mk & on;
        const bool moff = mk & (!on);
        out_sm[idx]   = mk ? score : 0.0f;
        out_on[idx]   = mon ? 1.0f : 0.0f;
        out_off[idx]  = moff ? 1.0f : 0.0f;
        unsigned long long bOn  = __ballot(mon);
        unsigned long long bOff = __ballot(moff);
        if (lane == 0) {
            hitOn [(size_t)p * NWORDS + word] = bOn;
            hitOff[(size_t)p * NWORDS + word] = bOff;
        }
    }
}

// ---------------------------------------------------------------------------
// Pool, round-14 form (kept): PLANE-OWNER GATHER. Block = (plane, side,
// chunk/16); scan 256 ballot words (coalesced 512B/wave + ballot/shfl walk),
// one coalesced 256B gather h2[n*64+lane] per hit (ILP-2), 4-wave LDS
// reduce, 1 atomicMax per dim (262K atomics, <=16 contenders/address).
// fmax order-independent -> bit-identical. ~30us.
// ---------------------------------------------------------------------------
__global__ __launch_bounds__(256) void pool_kernel(
    const float* __restrict__ h2,
    const unsigned long long* __restrict__ hitOn,
    const unsigned long long* __restrict__ hitOff,
    int* __restrict__ out_feats_i)
{
    __shared__ float sacc[4][DD];
    const int t = threadIdx.x;
    const int lane = t & 63;
    const int wv = t >> 6;

    const int bid   = blockIdx.x;          // 4096 = 128 planes * 2 sides * 16 chunks
    const int p     = bid >> 5;
    const int side  = (bid >> 4) & 1;
    const int chunk = bid & 15;
    const unsigned long long* hsrc = side ? hitOff : hitOn;

    // this wave's 64 words of the plane's ballot bitmap (coalesced 512B)
    const int wbase = chunk * 256 + wv * 64;
    const unsigned long long myw = hsrc[(size_t)p * NWORDS + wbase + lane];

    float acc = 0.0f;
    unsigned long long act = __ballot(myw != 0ULL);
    while (act) {
        const int l = __builtin_ctzll(act);
        act &= act - 1;
        unsigned long long w = __shfl(myw, l, 64);   // wave-uniform word
        const size_t nbase = (size_t)(wbase + l) * 64;
        while (w) {
            const int b0 = __builtin_ctzll(w); w &= w - 1;
            if (w) {
                const int b1 = __builtin_ctzll(w); w &= w - 1;
                const float v0 = h2[(nbase + b0) * DD + lane];
                const float v1 = h2[(nbase + b1) * DD + lane];
                acc = fmaxf(acc, v0);
                acc = fmaxf(acc, v1);
            } else {
                const float v0 = h2[(nbase + b0) * DD + lane];
                acc = fmaxf(acc, v0);
            }
        }
    }

    sacc[wv][lane] = acc;
    __syncthreads();
    if (t < DD) {
        const float m = fmaxf(fmaxf(sacc[0][t], sacc[1][t]),
                              fmaxf(sacc[2][t], sacc[3][t]));
        if (m != 0.0f)
            atomicMax(&out_feats_i[side * NP * DD + p * DD + t], __float_as_int(m));
    }
}

extern "C" void kernel_launch(void* const* d_in, const int* in_sizes, int n_in,
                              void* d_out, int out_size, void* d_ws, size_t ws_size,
                              hipStream_t stream) {
    const float* feature      = (const float*)d_in[0];
    const float* feature_geo  = (const float*)d_in[1];
    const float* xyz          = (const float*)d_in[2];
    const float* centers      = (const float*)d_in[3];
    const float* plane_center = (const float*)d_in[4];
    const float* plane_normal = (const float*)d_in[5];
    const float* pmin         = (const float*)d_in[6];
    const float* pmax         = (const float*)d_in[7];
    const float* w1 = (const float*)d_in[8];
    const float* b1 = (const float*)d_in[9];
    const float* g1 = (const float*)d_in[10];
    const float* be1 = (const float*)d_in[11];
    const float* m1 = (const float*)d_in[12];
    const float* v1 = (const float*)d_in[13];
    const float* w2 = (const float*)d_in[14];
    const float* b2 = (const float*)d_in[15];
    const float* g2 = (const float*)d_in[16];
    const float* be2 = (const float*)d_in[17];
    const float* m2 = (const float*)d_in[18];
    const float* v2 = (const float*)d_in[19];
    const float* w3 = (const float*)d_in[20];
    const float* b3 = (const float*)d_in[21];

    float* out = (float*)d_out;
    const size_t PN = (size_t)NP * NPTS;
    float* out_sm    = out;
    float* out_mask  = out + PN;
    float* out_on    = out + 2 * PN;
    float* out_off   = out + 3 * PN;
    float* out_feats = out + 4 * PN;

    // workspace carve (~73 MB)
    float* h2     = (float*)d_ws;                                // N*64 f32 (64 MB)
    unsigned long long* hitOn  = (unsigned long long*)(h2 + (size_t)NPTS * DD);
    unsigned long long* hitOff = hitOn + (size_t)NP * NWORDS;
    float* packed = (float*)(hitOff + (size_t)NP * NWORDS);      // 1280 f32 (SoA)
    float* w2T    = packed + NP * 12;                            // 64*64 f32

    prep_kernel<<<64, 256, 0, stream>>>(
        plane_center, plane_normal, pmin, pmax, w2, packed, w2T, out_feats);
    fused_kernel<<<NPTS / 256, 256, 0, stream>>>(
        feature, feature_geo, xyz, centers, packed,
        w1, b1, g1, be1, m1, v1, w2T, b2, g2, be2, m2, v2, w3, b3,
        h2, out_sm, out_mask, out_on, out_off, hitOn, hitOff);
    pool_kernel<<<4096, 256, 0, stream>>>(h2, hitOn, hitOff, (int*)out_feats);
}